// Round 7
// baseline (443.542 us; speedup 1.0000x reference)
//
#include <hip/hip_runtime.h>
#include <stdint.h>

#define NB 2
#define SL 4096
#define NH 16
#define HD 128
#define DS 256
#define CK 256
#define NCH 16
#define NSQ 4
#define DI 2048

#define EPST 132   // epilogue LDS row stride (u16): conflict-free repack

typedef unsigned short u16;
typedef unsigned int u32;
typedef __attribute__((ext_vector_type(8))) __bf16 bf16x8;
typedef __attribute__((ext_vector_type(4))) float f32x4;

__device__ __forceinline__ int tor(int dir, int t) { return dir ? (SL - 1 - t) : t; }

__device__ __forceinline__ u16 f2bf(float f) {
  u32 u = __float_as_uint(f);
  u = u + 0x7fffu + ((u >> 16) & 1u);   // RNE
  return (u16)(u >> 16);
}
__device__ __forceinline__ float bf2f(u16 s) {
  return __uint_as_float(((u32)s) << 16);
}

// ==== 128x32 tile helpers (BK=32), LDS [row][32] with 16B-chunk XOR by (row>>1)&3
struct Stg { uint4 a, b; };

__device__ __forceinline__ Stg ld_tile(const u16* __restrict__ src, int row, int q0, int k0) {
  const uint4* p = (const uint4*)(src + (size_t)row * 256 + k0 + (q0 << 3));
  Stg s; s.a = p[0]; s.b = p[1]; return s;
}
__device__ __forceinline__ void st_tile(u16* buf, int row, int q0, Stg s) {
  int sw = (row >> 1) & 3;
  *(uint4*)&buf[row * 32 + ((q0 ^ sw) << 3)] = s.a;
  *(uint4*)&buf[row * 32 + (((q0 + 1) ^ sw) << 3)] = s.b;
}
__device__ __forceinline__ bf16x8 frag(const u16* lds, int base_row, int m, int quad) {
  int row = base_row + m;
  return *(const bf16x8*)&lds[row * 32 + ((quad ^ ((row >> 1) & 3)) << 3)];
}
__device__ __forceinline__ void mfma16(const u16* As, const u16* Bs, int wi, int wp,
                                       int m, int quad, f32x4 acc[4][4]) {
  bf16x8 af[4], bv[4];
#pragma unroll
  for (int r = 0; r < 4; ++r) af[r] = frag(As, wi + (r << 4), m, quad);
#pragma unroll
  for (int c = 0; c < 4; ++c) bv[c] = frag(Bs, wp + (c << 4), m, quad);
#pragma unroll
  for (int r = 0; r < 4; ++r)
#pragma unroll
    for (int c = 0; c < 4; ++c)
      acc[r][c] = __builtin_amdgcn_mfma_f32_16x16x32_bf16(af[r], bv[c], acc[r][c], 0, 0, 0);
}

// ==== 128x64 tile helpers (BK=64), LDS [row][64] with 16B-chunk XOR by (row&7)
struct Stg64 { uint4 v[4]; };

__device__ __forceinline__ Stg64 ld_t64(const u16* __restrict__ src, int row, int half, int k0) {
  const uint4* p = (const uint4*)(src + (size_t)row * 256 + k0 + half * 32);
  Stg64 s;
#pragma unroll
  for (int c = 0; c < 4; ++c) s.v[c] = p[c];
  return s;
}
__device__ __forceinline__ void st_t64(u16* buf, int row, int half, Stg64 s) {
  int sw = row & 7;
#pragma unroll
  for (int c = 0; c < 4; ++c)
    *(uint4*)&buf[row * 64 + (((half * 4 + c) ^ sw) << 3)] = s.v[c];
}
__device__ __forceinline__ bf16x8 frag64(const u16* lds, int base_row, int m, int quad, int cb) {
  int row = base_row + m;
  return *(const bf16x8*)&lds[row * 64 + (((cb + quad) ^ (row & 7)) << 3)];
}
__device__ __forceinline__ void mfma64(const u16* As, const u16* Bs, int wi, int wp,
                                       int m, int quad, f32x4 acc[4][4]) {
#pragma unroll
  for (int cb = 0; cb < 8; cb += 4) {
    bf16x8 af[4], bv[4];
#pragma unroll
    for (int r = 0; r < 4; ++r) af[r] = frag64(As, wi + (r << 4), m, quad, cb);
#pragma unroll
    for (int c = 0; c < 4; ++c) bv[c] = frag64(Bs, wp + (c << 4), m, quad, cb);
#pragma unroll
    for (int r = 0; r < 4; ++r)
#pragma unroll
      for (int c = 0; c < 4; ++c)
        acc[r][c] = __builtin_amdgcn_mfma_f32_16x16x32_bf16(af[r], bv[c], acc[r][c], 0, 0, 0);
  }
}

// ---- prep: softplus(dt), per-chunk cumsum of dA -----------------------------
__global__ __launch_bounds__(256) void kprep(const float* __restrict__ dt,
                                             const float* __restrict__ A_log,
                                             float* __restrict__ csb,
                                             float* __restrict__ dtvb,
                                             float* __restrict__ cdecb) {
  int blk = blockIdx.x;                 // sj*16 + h
  int h = blk & 15, sj = blk >> 4;
  int s = sj >> 4, j = sj & 15;
  int b = s & 1, dir = s >> 1;
  int i = threadIdx.x;
  int to = tor(dir, j * CK + i);
  __shared__ float sbuf[CK];
  float a = -expf(A_log[h]);
  float raw = dt[((size_t)(b * SL + to)) * (2 * NH) + dir * NH + h];
  float sp = (raw > 20.f) ? raw : log1pf(expf(raw));
  sbuf[i] = sp * a;
  __syncthreads();
  for (int off = 1; off < CK; off <<= 1) {
    float v = (i >= off) ? sbuf[i - off] : 0.f;
    __syncthreads();
    sbuf[i] += v;
    __syncthreads();
  }
  float csv = sbuf[i];
  size_t base = ((size_t)sj * NH + h) * CK;
  csb[base + i] = csv;
  dtvb[base + i] = sp;
  if (i == CK - 1) cdecb[sj * NH + h] = expf(csv);
}

// ---- fused cast+transpose: BC -> Bbf/Cbf [s][t][n] and BbfT [sj][n][k] -------
__global__ __launch_bounds__(256) void kcastT(const float* __restrict__ BC,
                                              u16* __restrict__ Bbf,
                                              u16* __restrict__ Cbf,
                                              u16* __restrict__ BbfT) {
  int blk = blockIdx.x;                 // sj*4 + kq (k-quarter)
  int kq = blk & 3, sj = blk >> 2;
  int s = sj >> 4, j = sj & 15;
  int b = s & 1, dir = s >> 1;
  __shared__ u16 T[64 * 264];
  int tid = threadIdx.x;
  int r = tid >> 2, part = (tid & 3) * 64;
  int t = j * CK + kq * 64 + r;
  int tsrc = tor(dir, t);
  const float* src = BC + ((size_t)(b * SL + tsrc)) * (2 * DS);
  size_t dstb = ((size_t)s * SL + t) * DS;
  u16 bb[64], cc[64];
#pragma unroll
  for (int q = 0; q < 16; ++q) {
    float4 v = ((const float4*)(src + part))[q];
    bb[q * 4 + 0] = f2bf(v.x); bb[q * 4 + 1] = f2bf(v.y);
    bb[q * 4 + 2] = f2bf(v.z); bb[q * 4 + 3] = f2bf(v.w);
    float4 c = ((const float4*)(src + DS + part))[q];
    cc[q * 4 + 0] = f2bf(c.x); cc[q * 4 + 1] = f2bf(c.y);
    cc[q * 4 + 2] = f2bf(c.z); cc[q * 4 + 3] = f2bf(c.w);
  }
#pragma unroll
  for (int q = 0; q < 8; ++q) {
    ((uint4*)(Bbf + dstb + part))[q] = *(const uint4*)&bb[q * 8];
    ((uint4*)(Cbf + dstb + part))[q] = *(const uint4*)&cc[q * 8];
    *(uint4*)&T[r * 264 + part + q * 8] = *(const uint4*)&bb[q * 8];
  }
  __syncthreads();
  int n = tid;
  u16 col[64];
#pragma unroll
  for (int kk = 0; kk < 64; ++kk) col[kk] = T[kk * 264 + n];
  uint4* ds_ = (uint4*)(BbfT + (size_t)sj * DS * CK + (size_t)n * CK + kq * 64);
#pragma unroll
  for (int q = 0; q < 8; ++q) {
    uint4 wv;
    wv.x = (u32)col[q * 8 + 0] | ((u32)col[q * 8 + 1] << 16);
    wv.y = (u32)col[q * 8 + 2] | ((u32)col[q * 8 + 3] << 16);
    wv.z = (u32)col[q * 8 + 4] | ((u32)col[q * 8 + 5] << 16);
    wv.w = (u32)col[q * 8 + 6] | ((u32)col[q * 8 + 7] << 16);
    ds_[q] = wv;
  }
}

// ---- CBm[sj][i][k] = bf16( sum_n C[i,n]*B[k,n] ), masked k<=i ---------------
__global__ __launch_bounds__(256) void kcb(const u16* __restrict__ Cbf,
                                           const u16* __restrict__ Bbf,
                                           u16* __restrict__ CBm) {
  int blk = blockIdx.x;
  int tri = blk % 3;                    // 0:(0,0) 1:(1,0) 2:(1,1)
  int sj = blk / 3;
  int it0 = tri ? 128 : 0;
  int kt0 = (tri == 2) ? 128 : 0;
  int s = sj >> 4, j = sj & 15;
  __shared__ u16 smem[128 * EPST];
  int tid = threadIdx.x;
  int w = tid >> 6, lane = tid & 63;
  int wi = (w >> 1) << 6, wp = (w & 1) << 6;
  int m = lane & 15, quad = lane >> 4;
  int row = tid >> 1, q0 = (tid & 1) << 1;
  const u16* Ab = Cbf + ((size_t)s * SL + j * CK + it0) * DS;
  const u16* Bb = Bbf + ((size_t)s * SL + j * CK + kt0) * DS;
  f32x4 zini = {0.f, 0.f, 0.f, 0.f};
  f32x4 acc[4][4];
#pragma unroll
  for (int r = 0; r < 4; ++r)
#pragma unroll
    for (int c = 0; c < 4; ++c) acc[r][c] = zini;
  const int n = 8;
  Stg pa = ld_tile(Ab, row, q0, 0);
  Stg pb = ld_tile(Bb, row, q0, 0);
  st_tile(smem, row, q0, pa);
  st_tile(smem + 8192, row, q0, pb);
  pa = ld_tile(Ab, row, q0, 32);
  pb = ld_tile(Bb, row, q0, 32);
  for (int ks = 1; ks < n; ++ks) {
    __syncthreads();
    int cur = (ks & 1) << 12;
    st_tile(smem + cur, row, q0, pa);
    st_tile(smem + 8192 + cur, row, q0, pb);
    if (ks + 1 < n) {
      pa = ld_tile(Ab, row, q0, (ks + 1) << 5);
      pb = ld_tile(Bb, row, q0, (ks + 1) << 5);
    }
    int prv = ((ks - 1) & 1) << 12;
    mfma16(smem + prv, smem + 8192 + prv, wi, wp, m, quad, acc);
  }
  __syncthreads();
  {
    int prv = ((n - 1) & 1) << 12;
    mfma16(smem + prv, smem + 8192 + prv, wi, wp, m, quad, acc);
  }
  __syncthreads();
  int diag = (it0 == kt0);
#pragma unroll
  for (int r = 0; r < 4; ++r)
#pragma unroll
    for (int rg = 0; rg < 4; ++rg) {
      int irow = wi + (r << 4) + (quad << 2) + rg;
#pragma unroll
      for (int c = 0; c < 4; ++c) {
        int kcol = wp + (c << 4) + m;
        float v = acc[r][c][rg];
        if (diag && kcol > irow) v = 0.f;
        smem[irow * EPST + kcol] = f2bf(v);
      }
    }
  __syncthreads();
  {
    u16* dstb = CBm + ((size_t)sj * CK + it0) * CK + kt0;
    int rr = tid >> 1, off = (tid & 1) << 6;
    const uint4* srcv = (const uint4*)&smem[rr * EPST + off];
    uint4* dstv = (uint4*)(dstb + (size_t)rr * CK + off);
#pragma unroll
    for (int q = 0; q < 8; ++q) dstv[q] = srcv[q];
  }
}

// ---- fused: build xsT (scale+transpose of x) AND prevT = e^{cs_last}*xs·B^T --
// One block per inst=(sj,h). xs kept in LDS (8 tiles of 128x32, swizzled);
// phase 2 runs both 128x128 GEMMs with A read from LDS for free.
__global__ __launch_bounds__(256) void kxstates(const float* __restrict__ xg,
                                                const float* __restrict__ csb,
                                                const float* __restrict__ dtvb,
                                                const float* __restrict__ cdecb,
                                                const u16* __restrict__ BbfT,
                                                u16* __restrict__ xsT,
                                                u16* __restrict__ prevT) {
  int inst = blockIdx.x;                // sj*16 + h
  int h = inst & 15, sj = inst >> 4;
  int s = sj >> 4, j = sj & 15;
  int b = s & 1, dir = s >> 1;
  __shared__ u16 xs[8 * 4096];          // 64 KB: xs in 8 swizzled 128x32 tiles
  __shared__ u16 un[8192];              // 16 KB union: Ls (phase1) / B dbuf (phase2)
  int tid = threadIdx.x;

  // ---- phase 1: xs = bf16(x * e^{-cs} * dt), transposed; write xsT + LDS ----
  size_t cbase = ((size_t)sj * NH + h) * CK;
  u16* gdst = xsT + (size_t)inst * (128 * 256);
  int kk = tid >> 3;
  int pg = (tid & 7) * 16;
  int p2 = tid >> 1, half = tid & 1;
  float4 v[4];
  {
    int t = tor(dir, j * CK + kk);
    const float* src = xg + ((size_t)(b * SL + t)) * DI + h * HD + pg;
    v[0] = ((const float4*)src)[0]; v[1] = ((const float4*)src)[1];
    v[2] = ((const float4*)src)[2]; v[3] = ((const float4*)src)[3];
  }
  for (int k0 = 0; k0 < CK; k0 += 32) {
    int kglob = k0 + kk;
    float sc_ = expf(-csb[cbase + kglob]) * dtvb[cbase + kglob];
    float vv[16] = {v[0].x, v[0].y, v[0].z, v[0].w, v[1].x, v[1].y, v[1].z, v[1].w,
                    v[2].x, v[2].y, v[2].z, v[2].w, v[3].x, v[3].y, v[3].z, v[3].w};
    __syncthreads();
#pragma unroll
    for (int q = 0; q < 16; ++q) un[(pg + q) * 40 + kk] = f2bf(vv[q] * sc_);
    if (k0 + 32 < CK) {
      int t = tor(dir, j * CK + k0 + 32 + kk);
      const float* src = xg + ((size_t)(b * SL + t)) * DI + h * HD + pg;
      v[0] = ((const float4*)src)[0]; v[1] = ((const float4*)src)[1];
      v[2] = ((const float4*)src)[2]; v[3] = ((const float4*)src)[3];
    }
    __syncthreads();
    uint4 w0 = *(const uint4*)&un[p2 * 40 + half * 16];
    uint4 w1 = *(const uint4*)&un[p2 * 40 + half * 16 + 8];
    *(uint4*)&gdst[(size_t)p2 * 256 + k0 + half * 16] = w0;
    *(uint4*)&gdst[(size_t)p2 * 256 + k0 + half * 16 + 8] = w1;
    Stg sg; sg.a = w0; sg.b = w1;
    st_tile(xs + (k0 >> 5) * 4096, p2, half * 2, sg);
  }
  __syncthreads();

  // ---- phase 2: prevT[p][n] = scale * sum_k xs[p,k] * BbfT[n,k] -------------
  int w = tid >> 6, lane = tid & 63;
  int wi = (w >> 1) << 6, wp = (w & 1) << 6;
  int m = lane & 15, quad = lane >> 4;
  int row = tid >> 1, q0 = (tid & 1) << 1;
  float scale = cdecb[sj * NH + h];
  for (int ntile = 0; ntile < 2; ++ntile) {
    const u16* Bb = BbfT + ((size_t)sj * DS + (ntile << 7)) * CK;
    f32x4 zini = {0.f, 0.f, 0.f, 0.f};
    f32x4 acc[4][4];
#pragma unroll
    for (int r = 0; r < 4; ++r)
#pragma unroll
      for (int c = 0; c < 4; ++c) acc[r][c] = zini;
    Stg pb = ld_tile(Bb, row, q0, 0);
    st_tile(un, row, q0, pb);
    pb = ld_tile(Bb, row, q0, 32);
    for (int ks = 1; ks < 8; ++ks) {
      __syncthreads();
      st_tile(un + ((ks & 1) << 12), row, q0, pb);
      if (ks + 1 < 8) pb = ld_tile(Bb, row, q0, (ks + 1) << 5);
      mfma16(xs + ((ks - 1) << 12), un + (((ks - 1) & 1) << 12), wi, wp, m, quad, acc);
    }
    __syncthreads();
    mfma16(xs + (7 << 12), un + ((7 & 1) << 12), wi, wp, m, quad, acc);
    // epilogue: direct stores (lanes m consecutive in n -> 32B runs)
    u16* dstb = prevT + (size_t)inst * (128 * 256) + (ntile << 7);
#pragma unroll
    for (int r = 0; r < 4; ++r)
#pragma unroll
      for (int rg = 0; rg < 4; ++rg) {
        int prow = wi + (r << 4) + (quad << 2) + rg;
#pragma unroll
        for (int c = 0; c < 4; ++c) {
          int ncol = wp + (c << 4) + m;
          dstb[(size_t)prow * 256 + ncol] = f2bf(acc[r][c][rg] * scale);
        }
      }
    __syncthreads();   // un reused next ntile
  }
}

// ---- inter-chunk recurrence over prevT[s][j][h][p][n], 8 states per thread ---
__global__ __launch_bounds__(256) void kscan(u16* __restrict__ prevT,
                                             const float* __restrict__ cdecb) {
  int g = blockIdx.x * 256 + threadIdx.x;
  int n0 = (g & 31) * 8;
  int p = (g >> 5) & 127;
  int h = (g >> 12) & 15;
  int s = g >> 16;
  size_t base = ((size_t)(s * 256 + h) * 128 + p) * 256 + n0;
  const size_t stride = (size_t)NH * 128 * 256;
  float carry[8] = {0.f, 0.f, 0.f, 0.f, 0.f, 0.f, 0.f, 0.f};
  uint4 u = *(const uint4*)&prevT[base];
  for (int j = 0; j < NCH; ++j) {
    size_t idx = base + (size_t)j * stride;
    uint4 un;
    if (j + 1 < NCH) un = *(const uint4*)&prevT[idx + stride];
    u32 uu[4] = {u.x, u.y, u.z, u.w};
    float sv[8];
#pragma unroll
    for (int q = 0; q < 4; ++q) {
      sv[2 * q] = __uint_as_float(uu[q] << 16);
      sv[2 * q + 1] = __uint_as_float(uu[q] & 0xffff0000u);
    }
    uint4 wv;
    wv.x = (u32)f2bf(carry[0]) | ((u32)f2bf(carry[1]) << 16);
    wv.y = (u32)f2bf(carry[2]) | ((u32)f2bf(carry[3]) << 16);
    wv.z = (u32)f2bf(carry[4]) | ((u32)f2bf(carry[5]) << 16);
    wv.w = (u32)f2bf(carry[6]) | ((u32)f2bf(carry[7]) << 16);
    *(uint4*)&prevT[idx] = wv;
    float d = cdecb[(s * NCH + j) * NH + h];
#pragma unroll
    for (int q = 0; q < 8; ++q) carry[q] = carry[q] * d + sv[q];
    u = un;
  }
}

// ---- y[i,p] = e^{cs_i} * ( CBm(i,:)·xs(:,p) + C(i,:)·prev(:,p) ), BK=64 ------
__global__ __launch_bounds__(256) void ky(const u16* __restrict__ CBm,
                                          const u16* __restrict__ Cbf,
                                          const u16* __restrict__ xsT,
                                          const u16* __restrict__ prevT,
                                          const float* __restrict__ csb,
                                          u16* __restrict__ ytmpb) {
  int blk = blockIdx.x;
  int itile = blk & 1;
  int inst = blk >> 1;
  int h = inst & 15, sj = inst >> 4;
  int s = sj >> 4, j = sj & 15;
  int it0 = itile << 7;
  __shared__ u16 smem[32768];           // A dbuf @0/8192, B dbuf @16384/24576
  int tid = threadIdx.x;
  int w = tid >> 6, lane = tid & 63;
  int wi = (w >> 1) << 6, wp = (w & 1) << 6;
  int m = lane & 15, quad = lane >> 4;
  int row = tid >> 1, half = tid & 1;

  const u16* Ai = CBm + ((size_t)sj * CK + it0) * CK;
  const u16* Ae = Cbf + ((size_t)s * SL + j * CK + it0) * DS;
  const u16* Bi = xsT + (size_t)inst * (128 * 256);
  const u16* Be = prevT + (size_t)inst * (128 * 256);

  int nI = itile ? 4 : 2;               // BK=64 steps of intra (upper-zero skipped)
  int n = nI + 4;

  f32x4 zini = {0.f, 0.f, 0.f, 0.f};
  f32x4 acc[4][4];
#pragma unroll
  for (int r = 0; r < 4; ++r)
#pragma unroll
    for (int c = 0; c < 4; ++c) acc[r][c] = zini;

#define KY_SRC(ks)                                              \
  {                                                             \
    int intra_ = (ks) < nI;                                     \
    kk = (intra_ ? (ks) : (ks) - nI) << 6;                      \
    Ap = intra_ ? Ai : Ae;                                      \
    Bp = intra_ ? Bi : Be;                                      \
  }

  const u16 *Ap, *Bp; int kk;
  KY_SRC(0);
  Stg64 a1 = ld_t64(Ap, row, half, kk);
  Stg64 b1 = ld_t64(Bp, row, half, kk);
  st_t64(smem, row, half, a1);
  st_t64(smem + 16384, row, half, b1);
  KY_SRC(1);
  a1 = ld_t64(Ap, row, half, kk);
  b1 = ld_t64(Bp, row, half, kk);
  for (int ks = 1; ks < n; ++ks) {
    __syncthreads();
    int cur = (ks & 1) << 13;
    st_t64(smem + cur, row, half, a1);
    st_t64(smem + 16384 + cur, row, half, b1);
    if (ks + 1 < n) {
      KY_SRC(ks + 1);
      a1 = ld_t64(Ap, row, half, kk);
      b1 = ld_t64(Bp, row, half, kk);
    }
    int prv = ((ks - 1) & 1) << 13;
    mfma64(smem + prv, smem + 16384 + prv, wi, wp, m, quad, acc);
  }
  __syncthreads();
  {
    int prv = ((n - 1) & 1) << 13;
    mfma64(smem + prv, smem + 16384 + prv, wi, wp, m, quad, acc);
  }
  __syncthreads();
#undef KY_SRC

  const float* csrow = csb + ((size_t)sj * NH + h) * CK + it0;
#pragma unroll
  for (int r = 0; r < 4; ++r)
#pragma unroll
    for (int rg = 0; rg < 4; ++rg) {
      int irow = wi + (r << 4) + (quad << 2) + rg;
      float esc = expf(csrow[irow]);
#pragma unroll
      for (int c = 0; c < 4; ++c) {
        int pcol = wp + (c << 4) + m;
        smem[irow * EPST + pcol] = f2bf(acc[r][c][rg] * esc);
      }
    }
  __syncthreads();
  {
    u16* yb = ytmpb + ((size_t)s * SL + j * CK + it0) * DI + h * HD;
    int rr = tid >> 1, off = (tid & 1) << 6;
    const uint4* srcv = (const uint4*)&smem[rr * EPST + off];
    uint4* dstv = (uint4*)(yb + (size_t)rr * DI + off);
#pragma unroll
    for (int q = 0; q < 8; ++q) dstv[q] = srcv[q];
  }
}

// ---- gate[row][h] = sum_d x[row][d]*W[h][d] + D[h]; 8 rows per wave ----------
__global__ __launch_bounds__(256) void kgate(const float* __restrict__ xg,
                                             const float* __restrict__ Wg,
                                             const float* __restrict__ Dg,
                                             float* __restrict__ gate) {
  int wave = (blockIdx.x * 256 + threadIdx.x) >> 6;  // 1024 waves, 8 rows each
  int lane = threadIdx.x & 63;
  int gg = lane >> 4, h = lane & 15;
  int row0 = wave * 8;
  const float* xb = xg + (size_t)row0 * DI;
  float acc[8] = {0.f, 0.f, 0.f, 0.f, 0.f, 0.f, 0.f, 0.f};
  for (int q = 0; q < 128; ++q) {
    int d = gg * 4 + 16 * q;
    float4 wv = *(const float4*)&Wg[(size_t)h * DI + d];
#pragma unroll
    for (int r = 0; r < 8; ++r) {
      float4 xv = *(const float4*)&xb[(size_t)r * DI + d];
      acc[r] += xv.x * wv.x + xv.y * wv.y + xv.z * wv.z + xv.w * wv.w;
    }
  }
#pragma unroll
  for (int r = 0; r < 8; ++r) {
    acc[r] += __shfl_down(acc[r], 32);
    acc[r] += __shfl_down(acc[r], 16);
  }
  if (lane < 16) {
    float dv = Dg[h];
#pragma unroll
    for (int r = 0; r < 8; ++r) gate[(size_t)(row0 + r) * NH + h] = acc[r] + dv;
  }
}

// ---- combine: out[t] = y_fw[t-1] + y_bw[SL-2-t] + x[t]*gate ------------------
__device__ __forceinline__ void unpk8(uint4 u, float* o) {
  o[0] = __uint_as_float(u.x << 16); o[1] = __uint_as_float(u.x & 0xffff0000u);
  o[2] = __uint_as_float(u.y << 16); o[3] = __uint_as_float(u.y & 0xffff0000u);
  o[4] = __uint_as_float(u.z << 16); o[5] = __uint_as_float(u.z & 0xffff0000u);
  o[6] = __uint_as_float(u.w << 16); o[7] = __uint_as_float(u.w & 0xffff0000u);
}

__global__ __launch_bounds__(256) void kcombine(const float* __restrict__ xg,
                                                const float* __restrict__ gate,
                                                const u16* __restrict__ ytmpb,
                                                float* __restrict__ out) {
  int bid = blockIdx.x;
  int b = bid >> 12;
  int t = bid & (SL - 1);
  int tid = threadIdx.x;
  int d0 = tid * 8;
  float g = gate[(size_t)(b * SL + t) * NH + (tid >> 4)];
  float fy[8] = {0.f, 0.f, 0.f, 0.f, 0.f, 0.f, 0.f, 0.f};
  float by[8] = {0.f, 0.f, 0.f, 0.f, 0.f, 0.f, 0.f, 0.f};
  if (t > 0) {
    uint4 u = *(const uint4*)(ytmpb + ((size_t)(b * SL + (t - 1))) * DI + d0);
    unpk8(u, fy);
  }
  if (t < SL - 1) {
    uint4 u = *(const uint4*)(ytmpb + ((size_t)((2 + b) * SL + (SL - 2 - t))) * DI + d0);
    unpk8(u, by);
  }
  const float* xr = xg + ((size_t)(b * SL + t)) * DI + d0;
  float4 x0 = ((const float4*)xr)[0];
  float4 x1 = ((const float4*)xr)[1];
  float xa[8] = {x0.x, x0.y, x0.z, x0.w, x1.x, x1.y, x1.z, x1.w};
  float* op = out + ((size_t)(b * SL + t)) * DI + d0;
  float4 o0, o1;
  o0.x = fy[0] + by[0] + xa[0] * g; o0.y = fy[1] + by[1] + xa[1] * g;
  o0.z = fy[2] + by[2] + xa[2] * g; o0.w = fy[3] + by[3] + xa[3] * g;
  o1.x = fy[4] + by[4] + xa[4] * g; o1.y = fy[5] + by[5] + xa[5] * g;
  o1.z = fy[6] + by[6] + xa[6] * g; o1.w = fy[7] + by[7] + xa[7] * g;
  ((float4*)op)[0] = o0;
  ((float4*)op)[1] = o1;
}

extern "C" void kernel_launch(void* const* d_in, const int* in_sizes, int n_in,
                              void* d_out, int out_size, void* d_ws, size_t ws_size,
                              hipStream_t stream) {
  (void)in_sizes; (void)n_in; (void)out_size; (void)ws_size;
  const float* x     = (const float*)d_in[0];
  const float* BC    = (const float*)d_in[1];
  const float* dt    = (const float*)d_in[2];
  const float* A_log = (const float*)d_in[3];
  const float* Dg    = (const float*)d_in[4];
  const float* W     = (const float*)d_in[5];
  float* out = (float*)d_out;

  char* p = (char*)d_ws;
  float* cs   = (float*)p;  p += (size_t)NSQ * NCH * NH * CK * 4;        // 1 MB
  float* dtv  = (float*)p;  p += (size_t)NSQ * NCH * NH * CK * 4;        // 1 MB
  float* cdec = (float*)p;  p += (size_t)NSQ * NCH * NH * 4;             // 4 KB
  float* gateb= (float*)p;  p += (size_t)NB * SL * NH * 4;               // 512 KB
  u16* Bbf    = (u16*)p;    p += (size_t)NSQ * SL * DS * 2;              // 8.4 MB
  u16* Cbf    = (u16*)p;    p += (size_t)NSQ * SL * DS * 2;              // 8.4 MB
  u16* BbfT   = (u16*)p;    p += (size_t)NSQ * NCH * DS * CK * 2;        // 8.4 MB
  u16* CBm    = (u16*)p;    p += (size_t)NSQ * NCH * CK * CK * 2;        // 8.4 MB
  u16* xsT    = (u16*)p;    p += (size_t)NSQ * NCH * NH * HD * CK * 2;   // 67 MB
  u16* prevT  = (u16*)p;    p += (size_t)NSQ * NCH * NH * HD * DS * 2;   // 67 MB
  u16* ytmpb  = (u16*)p;    p += (size_t)NSQ * SL * DI * 2;              // 67 MB

  hipLaunchKernelGGL(kprep,    dim3(NSQ * NCH * NH),     dim3(CK),  0, stream, dt, A_log, cs, dtv, cdec);
  hipLaunchKernelGGL(kcastT,   dim3(NSQ * NCH * 4),      dim3(256), 0, stream, BC, Bbf, Cbf, BbfT);
  hipLaunchKernelGGL(kcb,      dim3(NSQ * NCH * 3),      dim3(256), 0, stream, Cbf, Bbf, CBm);
  hipLaunchKernelGGL(kxstates, dim3(NSQ * NCH * NH),     dim3(256), 0, stream, x, cs, dtv, cdec, BbfT, xsT, prevT);
  hipLaunchKernelGGL(kscan,    dim3(NSQ * NH * HD * DS / (256 * 8)), dim3(256), 0, stream, prevT, cdec);
  hipLaunchKernelGGL(ky,       dim3(NSQ * NCH * NH * 2), dim3(256), 0, stream, CBm, Cbf, xsT, prevT, cs, ytmpb);
  hipLaunchKernelGGL(kgate,    dim3(NB * SL / 32),       dim3(256), 0, stream, x, W, Dg, gateb);
  hipLaunchKernelGGL(kcombine, dim3(NB * SL),            dim3(256), 0, stream, x, gateb, ytmpb, out);
}